// Round 1
// baseline (13733.316 us; speedup 1.0000x reference)
//
#include <hip/hip_runtime.h>
#include <hip/hip_bf16.h>

#define T_STEPS 512
#define NB      64      // batch
#define NI      128     // input
#define NH      256     // hidden
#define LK      16      // short memory slots
#define RS      32      // long buckets
#define NS      (LK + RS)

// d_ws layout (floats)
#define WT_OFF   0                      // gates transposed+interleaved: [(k*256+h)*4 + g], k<384
#define WT_SZ    (384 * 4 * NH)         // 393216
#define UAT_OFF  (WT_OFF + WT_SZ)       // UaT[k*256+h] = Ua_w[h*256+k]
#define VAT_OFF  (UAT_OFF + NH * NH)    // VaT[k*256+h] = Va_w[h*256+k]
#define LRAW_OFF (VAT_OFF + NH * NH)    // per-sample long raw mem: [b][32][256]
#define LUA_OFF  (LRAW_OFF + NB * RS * NH)
// total = LUA_OFF + NB*RS*NH = 1,572,864 floats = 6 MB

__device__ __forceinline__ float fsig(float x) {
    // 1/(1+exp(-x)); exp overflow -> inf -> rcp -> 0 (correct limit)
    return __builtin_amdgcn_rcpf(1.0f + __expf(-x));
}
__device__ __forceinline__ float ftanh(float x) {
    x = fminf(15.0f, fmaxf(-15.0f, x));     // avoid inf/inf
    float e = __expf(2.0f * x);
    return (e - 1.0f) * __builtin_amdgcn_rcpf(e + 1.0f);
}

// Transpose/interleave weights into workspace (re-run every call: ws is re-poisoned).
__global__ void prep_weights(const float* __restrict__ Wf, const float* __restrict__ Wi,
                             const float* __restrict__ Wo, const float* __restrict__ Wg,
                             const float* __restrict__ Ua, const float* __restrict__ Va,
                             float* __restrict__ ws) {
    int e = blockIdx.x * 256 + threadIdx.x;
    if (e < WT_SZ) {
        int g = e & 3;
        int h = (e >> 2) & (NH - 1);
        int k = e >> 10;               // 0..383
        const float* W = (g == 0) ? Wf : (g == 1) ? Wi : (g == 2) ? Wo : Wg;
        ws[WT_OFF + e] = W[h * 384 + k];
    } else {
        int e2 = e - WT_SZ;            // 0..131071
        int h = e2 & (NH - 1);
        int k = (e2 >> 8) & (NH - 1);
        if (e2 < NH * NH)
            ws[UAT_OFF + e2] = Ua[h * NH + k];
        else
            ws[VAT_OFF + (e2 - NH * NH)] = Va[h * NH + k];
    }
}

// One block per batch sample; 256 threads; thread h owns hidden unit h.
__global__ __launch_bounds__(256) void rel_lstm(
    const float* __restrict__ x,
    const float* __restrict__ bf_g, const float* __restrict__ bi_g,
    const float* __restrict__ bo_g, const float* __restrict__ bg_g,
    const float* __restrict__ vv_g,
    float* __restrict__ ws, float* __restrict__ out) {
    const int tid = threadIdx.x;
    const int b   = blockIdx.x;

    const float4* W4 = (const float4*)(ws + WT_OFF);  // W4[k*256+h] = {f,i,o,g} weights
    const float* UaT = ws + UAT_OFF;
    const float* VaT = ws + VAT_OFF;
    float* lraw = ws + LRAW_OFF + b * (RS * NH);
    float* lua  = ws + LUA_OFF  + b * (RS * NH);

    __shared__ float s_st[NH], s_hid[NH], s_q[NH], s_x[NI], s_v[NH];
    __shared__ float s_mem[LK][NH];     // raw hidden ring
    __shared__ float s_memua[LK][NH];   // cached Ua@h for ring
    __shared__ float s_es[NS], s_al[NS];
    __shared__ float s_scores[T_STEPS];
    __shared__ float s_mask[RS], s_buck[RS];
    __shared__ int s_fill, s_upd, s_pos;

    // ---- init ----
    for (int j = 0; j < LK; j++) { s_mem[j][tid] = 0.f; s_memua[j][tid] = 0.f; }
    s_st[tid] = 0.f;
    s_scores[tid] = 0.f; s_scores[NH + tid] = 0.f;
    s_v[tid] = vv_g[tid];
    if (tid < RS) { s_mask[tid] = -1e30f; s_buck[tid] = 0.f; }
    if (tid == 0) { s_fill = 0; s_upd = 0; s_pos = 0; }
    for (int i = 0; i < RS; i++) { lraw[i * NH + tid] = 0.f; lua[i * NH + tid] = 0.f; }
    const float bf = bf_g[tid], bi = bi_g[tid], bo = bo_g[tid], bg = bg_g[tid];
    float ct = 0.f;
    int base = 0;

    // ---- step 0: st = 0, no attention ----
    if (tid < NI) s_x[tid] = x[b * NI + tid];
    __syncthreads();
    {
        float af = 0.f, ai = 0.f, ao = 0.f, ag = 0.f;
#pragma unroll 8
        for (int k = 0; k < NI; k++) {
            float s = s_x[k];
            float4 w = W4[(NH + k) * NH + tid];
            af += w.x * s; ai += w.y * s; ao += w.z * s; ag += w.w * s;
        }
        float f = fsig(af + bf), ii = fsig(ai + bi), o = fsig(ao + bo), g = ftanh(ag + bg);
        ct = ii * g;  // f * 0 + i*g
        float hid = o * ftanh(ct);
        s_hid[tid] = hid;
        out[b * NH + tid] = hid;
    }
    __syncthreads();
    {
        float acc = 0.f;
#pragma unroll 8
        for (int k = 0; k < NH; k++) acc += s_hid[k] * UaT[k * NH + tid];
        s_mem[0][tid] = s_hid[tid];
        s_memua[0][tid] = acc;
    }
    base = 1;
    __syncthreads();

    // ---- steps 1..511 ----
    for (int t = 1; t < T_STEPS; t++) {
        // Phase A: q = st_prev @ Va^T ; stage x_t
        {
            float q = 0.f;
#pragma unroll 8
            for (int k = 0; k < NH; k++) q += s_st[k] * VaT[k * NH + tid];
            s_q[tid] = q;
            if (tid < NI) s_x[tid] = x[(t * NB + b) * NI + tid];
        }
        __syncthreads();
        // Phase B: es over 48 slots (16 lanes per row, 4 rows per wave per iter)
        {
            const int wv = tid >> 6, lane = tid & 63, sub = lane >> 4, l = lane & 15;
            for (int it = 0; it < 3; it++) {
                int row = wv * 12 + it * 4 + sub;
                bool skip;
                if (row < LK) skip = (row < LK - t);                 // not yet filled (t<16)
                else          skip = (s_mask[row - LK] < -1e29f);    // empty bucket
                float esv = -1e30f;
                if (!skip) {
                    const float* ua = (row < LK) ? &s_memua[(base + row) & (LK - 1)][0]
                                                 : &lua[(row - LK) * NH];
                    float p = 0.f;
#pragma unroll 4
                    for (int hh = l; hh < NH; hh += 16)
                        p += s_v[hh] * ftanh(s_q[hh] + ua[hh]);
                    p += __shfl_xor(p, 1, 16);
                    p += __shfl_xor(p, 2, 16);
                    p += __shfl_xor(p, 4, 16);
                    p += __shfl_xor(p, 8, 16);
                    esv = p;  // long rows: mask==0 when filled
                }
                if (l == 0) s_es[row] = esv;
            }
        }
        __syncthreads();
        // softmax over 48 (wave 0)
        if (tid < 64) {
            float e = (tid < NS) ? s_es[tid] : -1e30f;
            float m = e;
            for (int off = 32; off; off >>= 1) m = fmaxf(m, __shfl_xor(m, off));
            float a = __expf(e - m);
            if (tid >= NS) a = 0.f;
            float ssum = a;
            for (int off = 32; off; off >>= 1) ssum += __shfl_xor(ssum, off);
            if (tid < NS) s_al[tid] = a * __builtin_amdgcn_rcpf(ssum);
        }
        __syncthreads();
        // Phase C: detached score accumulation + ct_att + st
        if (tid < LK) {
            int time = t - LK + tid;
            if (time >= 0) s_scores[time] += s_al[tid];
        }
        {
            int nf = s_fill;
            float catt = 0.f;
#pragma unroll
            for (int n = 0; n < LK; n++) catt += s_al[n] * s_mem[(base + n) & (LK - 1)][tid];
            for (int r = 0; r < nf; r++) catt += s_al[LK + r] * lraw[r * NH + tid];
            float stn = 0.5f * (s_mem[(base + LK - 1) & (LK - 1)][tid] + catt);
            s_st[tid] = stn;   // nobody reads s_st between phase A and here
        }
        __syncthreads();
        // Phase D: LSTM gates + pointwise
        {
            float af = 0.f, ai = 0.f, ao = 0.f, ag = 0.f;
#pragma unroll 8
            for (int k = 0; k < NH; k++) {
                float s = s_st[k];
                float4 w = W4[k * NH + tid];
                af += w.x * s; ai += w.y * s; ao += w.z * s; ag += w.w * s;
            }
#pragma unroll 8
            for (int k = 0; k < NI; k++) {
                float s = s_x[k];
                float4 w = W4[(NH + k) * NH + tid];
                af += w.x * s; ai += w.y * s; ao += w.z * s; ag += w.w * s;
            }
            float f = fsig(af + bf), ii = fsig(ai + bi), o = fsig(ao + bo), g = ftanh(ag + bg);
            ct = f * ct + ii * g;
            float hid = o * ftanh(ct);
            s_hid[tid] = hid;
            out[(t * NB + b) * NH + tid] = hid;
        }
        __syncthreads();
        // Phase E: cache Ua@hidden ; bucket decision (thread 0)
        float uan = 0.f;
#pragma unroll 8
        for (int k = 0; k < NH; k++) uan += s_hid[k] * UaT[k * NH + tid];
        if (tid == 0) {
            int upd = 0, pos = 0;
            if (t >= LK) {
                float cs = s_scores[t - LK];   // final: got its last addition this step
                int fill = s_fill;
                int full = (fill >= RS);
                float mv = s_buck[0]; int mp = 0;
                for (int r = 1; r < RS; r++) {  // first-min argmin
                    float bv = s_buck[r];
                    if (bv < mv) { mv = bv; mp = r; }
                }
                upd = (!full) || (cs > mv);
                pos = full ? mp : fill;
                if (upd) {
                    s_mask[pos] = 0.f;
                    s_buck[pos] = cs;
                    if (!full) s_fill = fill + 1;
                }
            }
            s_upd = upd; s_pos = pos;
        }
        __syncthreads();
        // Phase F: evict oldest into bucket (if chosen), push new hidden into ring
        {
            int p0 = base & (LK - 1);
            float oldraw = s_mem[p0][tid];
            float oldua  = s_memua[p0][tid];
            if (s_upd) {
                int pos = s_pos;
                lraw[pos * NH + tid] = oldraw;
                lua[pos * NH + tid]  = oldua;
            }
            s_mem[p0][tid]  = s_hid[tid];
            s_memua[p0][tid] = uan;
            base++;
        }
        __syncthreads();
    }
}

extern "C" void kernel_launch(void* const* d_in, const int* in_sizes, int n_in,
                              void* d_out, int out_size, void* d_ws, size_t ws_size,
                              hipStream_t stream) {
    const float* x  = (const float*)d_in[0];
    const float* Wf = (const float*)d_in[1];
    const float* bf = (const float*)d_in[2];
    const float* Wi = (const float*)d_in[3];
    const float* bi = (const float*)d_in[4];
    const float* Wo = (const float*)d_in[5];
    const float* bo = (const float*)d_in[6];
    const float* Wg = (const float*)d_in[7];
    const float* bg = (const float*)d_in[8];
    const float* Ua = (const float*)d_in[9];
    const float* Va = (const float*)d_in[10];
    const float* vv = (const float*)d_in[11];
    float* ws  = (float*)d_ws;
    float* out = (float*)d_out;

    // 524288 elements to transpose
    prep_weights<<<2048, 256, 0, stream>>>(Wf, Wi, Wo, Wg, Ua, Va, ws);
    rel_lstm<<<NB, 256, 0, stream>>>(x, bf, bi, bo, bg, vv, ws, out);
}

// Round 2
// 8205.648 us; speedup vs baseline: 1.6736x; 1.6736x over previous
//
#include <hip/hip_runtime.h>
#include <hip/hip_fp16.h>

#define T_STEPS 512
#define NB      64
#define NI      128
#define NH      256
#define LK      16
#define RS      32
#define NS      (LK + RS)

// ws layout (bytes)
#define WP_OFF   0            // uint4[192*256]: gate weights, k-pairs packed as 4 half2 (f,i,o,g)
#define VAP_OFF  786432       // __half2[128*256]: Va^T k-pairs
#define UAP_OFF  917504       // __half2[128*256]: Ua^T k-pairs
#define LRAW_OFF 1048576      // float[NB][RS][NH] raw long-term memory
#define LUA_OFF  3145728      // float[NB][RS][NH] cached Ua@long_mem
// total 5 MB

__device__ __forceinline__ float fsig(float x) {
    return __builtin_amdgcn_rcpf(1.0f + __expf(-x));
}
__device__ __forceinline__ float ftanh(float x) {
    x = fminf(15.0f, fmaxf(-15.0f, x));
    float e = __expf(2.0f * x);
    return (e - 1.0f) * __builtin_amdgcn_rcpf(e + 1.0f);
}

__global__ void prep_weights(const float* __restrict__ Wf, const float* __restrict__ Wi,
                             const float* __restrict__ Wo, const float* __restrict__ Wg,
                             const float* __restrict__ Ua, const float* __restrict__ Va,
                             unsigned char* __restrict__ ws) {
    int e = blockIdx.x * 256 + threadIdx.x;
    if (e < 192 * 256) {
        int h = e & 255, k2 = e >> 8, k = 2 * k2;
        uint4 w;
        __half2 t;
        t = __floats2half2_rn(Wf[h * 384 + k], Wf[h * 384 + k + 1]); w.x = *(unsigned int*)&t;
        t = __floats2half2_rn(Wi[h * 384 + k], Wi[h * 384 + k + 1]); w.y = *(unsigned int*)&t;
        t = __floats2half2_rn(Wo[h * 384 + k], Wo[h * 384 + k + 1]); w.z = *(unsigned int*)&t;
        t = __floats2half2_rn(Wg[h * 384 + k], Wg[h * 384 + k + 1]); w.w = *(unsigned int*)&t;
        ((uint4*)(ws + WP_OFF))[e] = w;
    } else if (e < 192 * 256 + 2 * 128 * 256) {
        int e2 = e - 192 * 256;
        const float* S = (e2 < 128 * 256) ? Va : Ua;
        int e3 = e2 & (128 * 256 - 1);
        int h = e3 & 255, k2 = e3 >> 8;
        __half2 t = __floats2half2_rn(S[h * 256 + 2 * k2], S[h * 256 + 2 * k2 + 1]);
        ((__half2*)(ws + VAP_OFF))[e2] = t;   // VaP then UaP contiguous
    }
}

// One block (1024 threads, 16 waves) per batch sample.
__global__ __launch_bounds__(1024, 1) void rel_lstm(
    const float* __restrict__ x,
    const float* __restrict__ bf_g, const float* __restrict__ bi_g,
    const float* __restrict__ bo_g, const float* __restrict__ bg_g,
    const float* __restrict__ vv_g,
    unsigned char* __restrict__ ws, float* __restrict__ out) {
    const int tid  = threadIdx.x;
    const int b    = blockIdx.x;
    const int role = tid >> 8;     // 0..3
    const int h    = tid & 255;

    const uint4*   __restrict__ WP  = (const uint4*)(ws + WP_OFF);
    const __half2* __restrict__ VaP = (const __half2*)(ws + VAP_OFF);
    const __half2* __restrict__ UaP = (const __half2*)(ws + UAP_OFF);
    float* __restrict__ lraw = (float*)(ws + LRAW_OFF) + b * (RS * NH);
    float* __restrict__ lua  = (float*)(ws + LUA_OFF)  + b * (RS * NH);

    __shared__ __align__(16) float s_in[NH + NI];     // [st | x]
    __shared__ float s_q[NH], s_hid[NH], s_v[NH];
    __shared__ float s_mem[LK][NH];
    __shared__ float s_memua[LK][NH + 4];             // +4 pad: break cross-row bank conflicts
    __shared__ __align__(16) float4 s_part4[1024];
    __shared__ float s_es[NS], s_al[NS];
    __shared__ float s_scores[T_STEPS];
    __shared__ float s_mask[RS], s_buck[RS];
    __shared__ int s_fill, s_upd, s_pos;
    float* s_partf = (float*)s_part4;

    // ---- init ----
    for (int j = 0; j < 4; ++j) { s_mem[role * 4 + j][h] = 0.f; s_memua[role * 4 + j][h] = 0.f; }
    if (tid < 512) s_scores[tid] = 0.f;
    if (tid < NH) { s_v[tid] = vv_g[tid]; s_in[tid] = 0.f; }
    if (tid < RS) { s_mask[tid] = -1e30f; s_buck[tid] = 0.f; }
    if (tid == 0) { s_fill = 0; s_upd = 0; s_pos = 0; }
    if (tid < 32) ((float4*)(s_in + NH))[tid] = ((const float4*)(x + b * NI))[tid];
    float bfv = 0.f, biv = 0.f, bov = 0.f, bgv = 0.f;
    if (tid < NH) { bfv = bf_g[h]; biv = bi_g[h]; bov = bo_g[h]; bgv = bg_g[h]; }
    float ct = 0.f;
    int base = 0;
    __syncthreads();

    // ---- step 0: st = 0, gates on [0|x] ----
    {
        float af = 0.f, ai = 0.f, ao = 0.f, ag = 0.f;
        int lo = role * 48;
#pragma unroll 8
        for (int k2 = lo; k2 < lo + 48; ++k2) {
            float2 ss = *(const float2*)(s_in + 2 * k2);
            uint4 w = WP[k2 * NH + h];
            float2 f0 = __half22float2(*(const __half2*)&w.x);
            float2 f1 = __half22float2(*(const __half2*)&w.y);
            float2 f2 = __half22float2(*(const __half2*)&w.z);
            float2 f3 = __half22float2(*(const __half2*)&w.w);
            af += f0.x * ss.x + f0.y * ss.y;
            ai += f1.x * ss.x + f1.y * ss.y;
            ao += f2.x * ss.x + f2.y * ss.y;
            ag += f3.x * ss.x + f3.y * ss.y;
        }
        s_part4[role * NH + h] = make_float4(af, ai, ao, ag);
    }
    __syncthreads();
    if (tid < NH) {
        float4 a = s_part4[h], b4 = s_part4[NH + h], c4 = s_part4[2 * NH + h], d4 = s_part4[3 * NH + h];
        float f  = fsig(a.x + b4.x + c4.x + d4.x + bfv);
        float ii = fsig(a.y + b4.y + c4.y + d4.y + biv);
        float o  = fsig(a.z + b4.z + c4.z + d4.z + bov);
        float g  = ftanh(a.w + b4.w + c4.w + d4.w + bgv);
        ct = ii * g;                          // f * 0 + i*g
        float hid = o * ftanh(ct);
        s_hid[h] = hid;
        out[b * NH + h] = hid;
        s_mem[0][h] = hid;
    }
    base++;   // = 1
    __syncthreads();

    // ---- steps 1..511 ----
    for (int t = 1; t < T_STEPS; ++t) {
        // S1: roles 0,1 -> q = st@Va^T partials; roles 2,3 -> uan = hid@Ua^T partials; stage x_t
        {
            const __half2* P  = (role < 2) ? VaP : UaP;
            const float* src  = (role < 2) ? s_in : s_hid;
            int lo = (role & 1) * 64;
            float p = 0.f;
#pragma unroll 8
            for (int k2 = lo; k2 < lo + 64; ++k2) {
                float2 wv = __half22float2(P[k2 * NH + h]);
                float2 ss = *(const float2*)(src + 2 * k2);
                p += wv.x * ss.x + wv.y * ss.y;
            }
            s_partf[tid] = p;
            if (tid < 32) ((float4*)(s_in + NH))[tid] = ((const float4*)(x + (t * NB + b) * NI))[tid];
        }
        __syncthreads();
        // S2: combine q; write cached Ua@h_{t-1} into newest ring slot
        if (tid < NH) s_q[h] = s_partf[h] + s_partf[NH + h];
        else if (tid < 512) s_memua[(base + LK - 1) & (LK - 1)][h] = s_partf[512 + h] + s_partf[768 + h];
        __syncthreads();
        // S3: attention scores, 48 rows x 16 lanes
        if (tid < 768) {
            int row = ((tid >> 6) << 2) + ((tid >> 4) & 3);
            int l = tid & 15;
            bool skip;
            const float* ua;
            if (row < LK) { skip = row < LK - t; ua = s_memua[(base + row) & (LK - 1)]; }
            else          { skip = s_mask[row - LK] < -1e29f; ua = lua + (row - LK) * NH; }
            float esv = -1e30f;
            if (!skip) {
                float p = 0.f;
#pragma unroll
                for (int j = 0; j < 16; ++j) {
                    int hh = l + (j << 4);
                    p += s_v[hh] * ftanh(s_q[hh] + ua[hh]);
                }
                p += __shfl_xor(p, 1, 16);
                p += __shfl_xor(p, 2, 16);
                p += __shfl_xor(p, 4, 16);
                p += __shfl_xor(p, 8, 16);
                esv = p;
            }
            if (l == 0) s_es[row] = esv;
        }
        __syncthreads();
        // S4: softmax over 48 (wave 0)
        if (tid < 64) {
            float e = (tid < NS) ? s_es[tid] : -1e30f;
            float m = e;
            for (int off = 32; off; off >>= 1) m = fmaxf(m, __shfl_xor(m, off));
            float a = (tid < NS) ? __expf(e - m) : 0.f;
            float ssum = a;
            for (int off = 32; off; off >>= 1) ssum += __shfl_xor(ssum, off);
            if (tid < NS) s_al[tid] = a * __builtin_amdgcn_rcpf(ssum);
        }
        __syncthreads();
        // S5: ct_att partials (12 slots per role) + detached score accumulation
        {
            float catt = 0.f;
            int n0 = role * 12;
#pragma unroll
            for (int n = n0; n < n0 + 12; ++n) {
                float a = s_al[n];
                if (n < LK) catt += a * s_mem[(base + n) & (LK - 1)][h];
                else if (a != 0.f) catt += a * lraw[(n - LK) * NH + h];
            }
            s_partf[tid] = catt;
            if (tid < LK) {
                int time = t - LK + tid;
                if (time >= 0) s_scores[time] += s_al[tid];
            }
        }
        __syncthreads();
        // S6: combine -> st; bucket decision (thread 1023)
        if (tid < NH) {
            float catt = s_partf[h] + s_partf[NH + h] + s_partf[2 * NH + h] + s_partf[3 * NH + h];
            s_in[h] = 0.5f * (s_mem[(base + LK - 1) & (LK - 1)][h] + catt);
        } else if (tid == 1023) {
            int upd = 0, pos = 0;
            if (t >= LK) {
                float cs = s_scores[t - LK];
                int fill = s_fill;
                bool full = fill >= RS;
                float mv = s_buck[0]; int mp = 0;
                for (int r = 1; r < RS; ++r) { float bv = s_buck[r]; if (bv < mv) { mv = bv; mp = r; } }
                upd = (!full) || (cs > mv);
                pos = full ? mp : fill;
                if (upd) { s_mask[pos] = 0.f; s_buck[pos] = cs; if (!full) s_fill = fill + 1; }
            }
            s_upd = upd; s_pos = pos;
        }
        __syncthreads();
        // S7: gate matvec partials (4-way k-split); role 3 also evicts oldest into bucket
        {
            float af = 0.f, ai = 0.f, ao = 0.f, ag = 0.f;
            int lo = role * 48;
#pragma unroll 8
            for (int k2 = lo; k2 < lo + 48; ++k2) {
                float2 ss = *(const float2*)(s_in + 2 * k2);
                uint4 w = WP[k2 * NH + h];
                float2 f0 = __half22float2(*(const __half2*)&w.x);
                float2 f1 = __half22float2(*(const __half2*)&w.y);
                float2 f2 = __half22float2(*(const __half2*)&w.z);
                float2 f3 = __half22float2(*(const __half2*)&w.w);
                af += f0.x * ss.x + f0.y * ss.y;
                ai += f1.x * ss.x + f1.y * ss.y;
                ao += f2.x * ss.x + f2.y * ss.y;
                ag += f3.x * ss.x + f3.y * ss.y;
            }
            s_part4[role * NH + h] = make_float4(af, ai, ao, ag);
            if (role == 3 && s_upd) {
                int p0 = base & (LK - 1), pos = s_pos;
                lraw[pos * NH + h] = s_mem[p0][h];
                lua[pos * NH + h]  = s_memua[p0][h];
            }
        }
        __syncthreads();
        // S8: combine + activations + output + ring push
        if (tid < NH) {
            float4 a = s_part4[h], b4 = s_part4[NH + h], c4 = s_part4[2 * NH + h], d4 = s_part4[3 * NH + h];
            float f  = fsig(a.x + b4.x + c4.x + d4.x + bfv);
            float ii = fsig(a.y + b4.y + c4.y + d4.y + biv);
            float o  = fsig(a.z + b4.z + c4.z + d4.z + bov);
            float g  = ftanh(a.w + b4.w + c4.w + d4.w + bgv);
            ct = f * ct + ii * g;
            float hid = o * ftanh(ct);
            s_hid[h] = hid;
            out[(t * NB + b) * NH + h] = hid;
            s_mem[base & (LK - 1)][h] = hid;
        }
        base++;
        __syncthreads();
    }
}

extern "C" void kernel_launch(void* const* d_in, const int* in_sizes, int n_in,
                              void* d_out, int out_size, void* d_ws, size_t ws_size,
                              hipStream_t stream) {
    const float* x  = (const float*)d_in[0];
    const float* Wf = (const float*)d_in[1];
    const float* bf = (const float*)d_in[2];
    const float* Wi = (const float*)d_in[3];
    const float* bi = (const float*)d_in[4];
    const float* Wo = (const float*)d_in[5];
    const float* bo = (const float*)d_in[6];
    const float* Wg = (const float*)d_in[7];
    const float* bg = (const float*)d_in[8];
    const float* Ua = (const float*)d_in[9];
    const float* Va = (const float*)d_in[10];
    const float* vv = (const float*)d_in[11];
    unsigned char* ws = (unsigned char*)d_ws;
    float* out = (float*)d_out;

    prep_weights<<<448, 256, 0, stream>>>(Wf, Wi, Wo, Wg, Ua, Va, ws);
    rel_lstm<<<NB, 1024, 0, stream>>>(x, bf, bi, bo, bg, vv, ws, out);
}

// Round 3
// 7973.109 us; speedup vs baseline: 1.7225x; 1.0292x over previous
//
#include <hip/hip_runtime.h>
#include <hip/hip_fp16.h>

#define T_STEPS 512
#define NB      64
#define NI      128
#define NH      256
#define LK      16
#define RS      32
#define NS      (LK + RS)

// ws layout (bytes)
#define WP_OFF   0            // uint4[192*256]: gate weights, k-pairs packed as 4 half2 (f,i,o,g)
#define VAP8_OFF 786432       // uint4[32*256]: Va^T, 8 consecutive k per entry, per output h
#define UAP8_OFF 917504       // uint4[32*256]: Ua^T, same layout
#define LRAW_OFF 1048576      // float[NB][RS][NH]
#define LUA_OFF  3145728      // float[NB][RS][NH]
#define GX_OFF   5242880      // fp16 uint2[512*64*256]: precomputed x-part of gates (f,i,o,g)
#define WS_NEED  (GX_OFF + (size_t)T_STEPS * NB * NH * 8)

__device__ __forceinline__ float fsig(float x) {
    return __builtin_amdgcn_rcpf(1.0f + __expf(-x));
}
__device__ __forceinline__ float ftanh(float x) {
    x = fminf(15.0f, fmaxf(-15.0f, x));
    float e = __expf(2.0f * x);
    return (e - 1.0f) * __builtin_amdgcn_rcpf(e + 1.0f);
}

__global__ void prep_weights(const float* __restrict__ Wf, const float* __restrict__ Wi,
                             const float* __restrict__ Wo, const float* __restrict__ Wg,
                             const float* __restrict__ Ua, const float* __restrict__ Va,
                             unsigned char* __restrict__ ws) {
    int e = blockIdx.x * 256 + threadIdx.x;   // 0..65535
    if (e < 49152) {                          // WP: e = k2*256 + h
        int h = e & 255, k2 = e >> 8, k = 2 * k2;
        uint4 w; __half2 t;
        t = __floats2half2_rn(Wf[h * 384 + k], Wf[h * 384 + k + 1]); w.x = *(unsigned int*)&t;
        t = __floats2half2_rn(Wi[h * 384 + k], Wi[h * 384 + k + 1]); w.y = *(unsigned int*)&t;
        t = __floats2half2_rn(Wo[h * 384 + k], Wo[h * 384 + k + 1]); w.z = *(unsigned int*)&t;
        t = __floats2half2_rn(Wg[h * 384 + k], Wg[h * 384 + k + 1]); w.w = *(unsigned int*)&t;
        ((uint4*)(ws + WP_OFF))[e] = w;
    } else {                                  // Va/Ua 8-k packs
        int e2 = e - 49152;                   // 0..16383
        const float* S = (e2 < 8192) ? Va : Ua;
        int e3 = e2 & 8191;
        int h = e3 & 255, j = e3 >> 8, k = 8 * j;
        uint4 w; __half2 t;
        t = __floats2half2_rn(S[h * 256 + k + 0], S[h * 256 + k + 1]); w.x = *(unsigned int*)&t;
        t = __floats2half2_rn(S[h * 256 + k + 2], S[h * 256 + k + 3]); w.y = *(unsigned int*)&t;
        t = __floats2half2_rn(S[h * 256 + k + 4], S[h * 256 + k + 5]); w.z = *(unsigned int*)&t;
        t = __floats2half2_rn(S[h * 256 + k + 6], S[h * 256 + k + 7]); w.w = *(unsigned int*)&t;
        ((uint4*)(ws + VAP8_OFF))[e2] = w;    // VaP8 then UaP8 contiguous
    }
}

// Parallel GEMM: gate_x[t][b][h][4g] = W_x @ x_t  (x-part of gate pre-activations, no bias)
__global__ __launch_bounds__(256) void gx_gemm(const float* __restrict__ x,
                                               unsigned char* __restrict__ ws) {
    const int t = blockIdx.x, bg = blockIdx.y, tid = threadIdx.x;
    const uint4* __restrict__ WP = (const uint4*)(ws + WP_OFF);
    uint2* __restrict__ GX = (uint2*)(ws + GX_OFF);
    __shared__ float s_xx[16 * 128];          // [bb][k]
    const float* xb = x + ((size_t)t * NB + bg * 16) * NI;
#pragma unroll
    for (int r = 0; r < 8; ++r) s_xx[tid + 256 * r] = xb[tid + 256 * r];
    __syncthreads();
    const int h = tid;
    float acc[16][4];
#pragma unroll
    for (int bb = 0; bb < 16; ++bb) { acc[bb][0] = acc[bb][1] = acc[bb][2] = acc[bb][3] = 0.f; }
    for (int k2 = 128; k2 < 192; ++k2) {
        uint4 w = WP[k2 * NH + h];
        float2 wf = __half22float2(*(const __half2*)&w.x);
        float2 wi = __half22float2(*(const __half2*)&w.y);
        float2 wo = __half22float2(*(const __half2*)&w.z);
        float2 wg = __half22float2(*(const __half2*)&w.w);
        int kk = 2 * k2 - 256;
#pragma unroll
        for (int bb = 0; bb < 16; ++bb) {
            float2 xv = *(const float2*)(s_xx + bb * 128 + kk);
            acc[bb][0] += wf.x * xv.x + wf.y * xv.y;
            acc[bb][1] += wi.x * xv.x + wi.y * xv.y;
            acc[bb][2] += wo.x * xv.x + wo.y * xv.y;
            acc[bb][3] += wg.x * xv.x + wg.y * xv.y;
        }
    }
#pragma unroll
    for (int bb = 0; bb < 16; ++bb) {
        __half2 p0 = __floats2half2_rn(acc[bb][0], acc[bb][1]);
        __half2 p1 = __floats2half2_rn(acc[bb][2], acc[bb][3]);
        uint2 u; u.x = *(unsigned int*)&p0; u.y = *(unsigned int*)&p1;
        GX[((size_t)t * NB + bg * 16 + bb) * NH + h] = u;
    }
}

// One block (1024 threads, 16 waves) per batch sample.
template <int USE_GX>
__global__ __launch_bounds__(1024, 1) void rel_lstm(
    const float* __restrict__ x,
    const float* __restrict__ bf_g, const float* __restrict__ bi_g,
    const float* __restrict__ bo_g, const float* __restrict__ bg_g,
    const float* __restrict__ vv_g,
    unsigned char* __restrict__ ws, float* __restrict__ out) {
    const int tid  = threadIdx.x;
    const int b    = blockIdx.x;
    const int role = tid >> 8;
    const int h    = tid & 255;

    const uint4* __restrict__ WP   = (const uint4*)(ws + WP_OFF);
    const uint4* __restrict__ VaP8 = (const uint4*)(ws + VAP8_OFF);
    const uint4* __restrict__ UaP8 = (const uint4*)(ws + UAP8_OFF);
    const uint2* __restrict__ GX   = (const uint2*)(ws + GX_OFF);
    float* __restrict__ lraw = (float*)(ws + LRAW_OFF) + b * (RS * NH);
    float* __restrict__ lua  = (float*)(ws + LUA_OFF)  + b * (RS * NH);

    __shared__ __align__(16) float s_in[NH + NI];     // [st | x]
    __shared__ __align__(16) float s_hid[NH];
    __shared__ float s_v[NH];
    __shared__ float s_mem[LK][NH];
    __shared__ float s_memua[LK][NH + 8];             // +8 pad: 2-way max bank aliasing
    __shared__ __align__(16) float4 s_part4[1024];    // [0..255]:A-partials(float slots 0..1023)
    __shared__ float s_es[NS], s_al[NS];
    __shared__ float s_scores[T_STEPS];
    __shared__ float s_mask[RS], s_buck[RS];
    __shared__ float s_minv;
    __shared__ int s_minp, s_fill, s_upd, s_pos;
    float* s_partf = (float*)s_part4;

    // ---- init ----
    for (int j = 0; j < 4; ++j) { s_mem[role * 4 + j][h] = 0.f; s_memua[role * 4 + j][h] = 0.f; }
    if (tid < 512) s_scores[tid] = 0.f;
    if (tid < NH) { s_v[tid] = vv_g[tid]; s_in[tid] = 0.f; }
    if (tid < RS) { s_mask[tid] = -1e30f; s_buck[tid] = 0.f; }
    if (tid == 0) { s_fill = 0; s_upd = 0; s_pos = 0; s_minv = 0.f; s_minp = 0; }
    if (!USE_GX && tid < 32) ((float4*)(s_in + NH))[tid] = ((const float4*)(x + b * NI))[tid];
    float bfv = 0.f, biv = 0.f, bov = 0.f, bgv = 0.f;
    if (tid < NH) { bfv = bf_g[h]; biv = bi_g[h]; bov = bo_g[h]; bgv = bg_g[h]; }
    float ct = 0.f;
    int base = 0;
    __syncthreads();

    // ---- step 0: st = 0 -> gates are x-part + bias only ----
    if (USE_GX) {
        if (tid < NH) {
            uint2 g0 = GX[b * NH + h];
            float2 fi = __half22float2(*(const __half2*)&g0.x);
            float2 og = __half22float2(*(const __half2*)&g0.y);
            float f  = fsig(fi.x + bfv);
            float ii = fsig(fi.y + biv);
            float o  = fsig(og.x + bov);
            float g  = ftanh(og.y + bgv);
            ct = ii * g;
            float hid = o * ftanh(ct);
            s_hid[h] = hid; out[b * NH + h] = hid; s_mem[0][h] = hid;
        }
    } else {
        float af = 0.f, ai = 0.f, ao = 0.f, ag = 0.f;
        int lo = 128 + role * 16;
#pragma unroll 8
        for (int k2 = lo; k2 < lo + 16; ++k2) {
            float2 ss = *(const float2*)(s_in + 2 * k2);
            uint4 w = WP[k2 * NH + h];
            float2 f0 = __half22float2(*(const __half2*)&w.x);
            float2 f1 = __half22float2(*(const __half2*)&w.y);
            float2 f2 = __half22float2(*(const __half2*)&w.z);
            float2 f3 = __half22float2(*(const __half2*)&w.w);
            af += f0.x * ss.x + f0.y * ss.y; ai += f1.x * ss.x + f1.y * ss.y;
            ao += f2.x * ss.x + f2.y * ss.y; ag += f3.x * ss.x + f3.y * ss.y;
        }
        s_part4[role * NH + h] = make_float4(af, ai, ao, ag);
        __syncthreads();
        if (tid < NH) {
            float4 A = s_part4[h], B4 = s_part4[NH + h], C4 = s_part4[2 * NH + h], D4 = s_part4[3 * NH + h];
            float f  = fsig(A.x + B4.x + C4.x + D4.x + bfv);
            float ii = fsig(A.y + B4.y + C4.y + D4.y + biv);
            float o  = fsig(A.z + B4.z + C4.z + D4.z + bov);
            float g  = ftanh(A.w + B4.w + C4.w + D4.w + bgv);
            ct = ii * g;
            float hid = o * ftanh(ct);
            s_hid[h] = hid; out[b * NH + h] = hid; s_mem[0][h] = hid;
        }
    }
    base = 1;
    __syncthreads();

    // ---- steps 1..511 ----
    for (int t = 1; t < T_STEPS; ++t) {
        uint2 gx;
        // A: Va@st partials (roles 0,1) and Ua@h_{t-1} partials (roles 2,3); 8-k uint4 loads
        {
            const uint4* P  = (role < 2) ? VaP8 : UaP8;
            const float* src = (role < 2) ? s_in : s_hid;
            int j0 = (role & 1) * 16;
            float p = 0.f;
#pragma unroll 8
            for (int j = j0; j < j0 + 16; ++j) {
                uint4 w = P[j * NH + h];
                float4 sa = *(const float4*)(src + 8 * j);
                float4 sb = *(const float4*)(src + 8 * j + 4);
                float2 w0 = __half22float2(*(const __half2*)&w.x);
                float2 w1 = __half22float2(*(const __half2*)&w.y);
                float2 w2 = __half22float2(*(const __half2*)&w.z);
                float2 w3 = __half22float2(*(const __half2*)&w.w);
                p += w0.x * sa.x + w0.y * sa.y + w1.x * sa.z + w1.y * sa.w
                   + w2.x * sb.x + w2.y * sb.y + w3.x * sb.z + w3.y * sb.w;
            }
            s_partf[tid] = p;
            if (USE_GX) {
                if (tid < NH) gx = GX[((size_t)t * NB + b) * NH + h];
            } else {
                if (tid < 32) ((float4*)(s_in + NH))[tid] = ((const float4*)(x + ((size_t)t * NB + b) * NI))[tid];
            }
        }
        __syncthreads();
        // B: attention scores (48 rows x 16 lanes, q/ua-combine inline); wave-15 lanes do bucket argmin
        if (tid < 768) {
            int row = ((tid >> 6) << 2) + ((tid >> 4) & 3);
            int l = tid & 15;
            bool skip, newest = false;
            const float* ua;
            if (row < LK) { skip = row < LK - t; newest = (row == LK - 1); ua = s_memua[(base + row) & (LK - 1)]; }
            else          { skip = s_mask[row - LK] < -1e29f; ua = lua + (row - LK) * NH; }
            float esv = -1e30f;
            if (!skip) {
                float p = 0.f;
#pragma unroll
                for (int jj = 0; jj < 16; ++jj) {
                    int hh = l + (jj << 4);
                    float qv = s_partf[hh] + s_partf[NH + hh];
                    float uav = newest ? (s_partf[512 + hh] + s_partf[768 + hh]) : ua[hh];
                    p += s_v[hh] * ftanh(qv + uav);
                }
                p += __shfl_xor(p, 1, 16);
                p += __shfl_xor(p, 2, 16);
                p += __shfl_xor(p, 4, 16);
                p += __shfl_xor(p, 8, 16);
                esv = p;
            }
            if (l == 0) s_es[row] = esv;
        } else if (tid >= 960 && tid < 992) {   // parallel first-min argmin over s_buck
            int l = tid - 960;
            float v = s_buck[l]; int idx = l;
#pragma unroll
            for (int off = 1; off < 32; off <<= 1) {
                float v2 = __shfl_xor(v, off, 32);
                int  i2 = __shfl_xor(idx, off, 32);
                if (v2 < v || (v2 == v && i2 < idx)) { v = v2; idx = i2; }
            }
            if (l == 0) { s_minv = v; s_minp = idx; }
        }
        __syncthreads();
        // C: softmax over 48 (wave 0)
        if (tid < 64) {
            float e = (tid < NS) ? s_es[tid] : -1e30f;
            float m = e;
            for (int off = 32; off; off >>= 1) m = fmaxf(m, __shfl_xor(m, off));
            float a = (tid < NS) ? __expf(e - m) : 0.f;
            float ssum = a;
            for (int off = 32; off; off >>= 1) ssum += __shfl_xor(ssum, off);
            if (tid < NS) s_al[tid] = a * __builtin_amdgcn_rcpf(ssum);
        }
        __syncthreads();
        // D: ct_att partials (12 slots/role) + detached score accumulation
        {
            float catt = 0.f;
            int n0 = role * 12;
#pragma unroll
            for (int n = n0; n < n0 + 12; ++n) {
                float a = s_al[n];
                if (n < LK) catt += a * s_mem[(base + n) & (LK - 1)][h];
                else if (a != 0.f) catt += a * lraw[(n - LK) * NH + h];
            }
            s_partf[1024 + tid] = catt;
            if (tid < LK) {
                int time = t - LK + tid;
                if (time >= 0) s_scores[time] += s_al[tid];
            }
        }
        __syncthreads();
        // E: st combine; persist Ua@h_{t-1} into newest ring slot; bucket decision
        if (tid < NH) {
            float catt = s_partf[1024 + h] + s_partf[1280 + h] + s_partf[1536 + h] + s_partf[1792 + h];
            s_in[h] = 0.5f * (s_mem[(base + LK - 1) & (LK - 1)][h] + catt);
        } else if (tid < 512) {
            s_memua[(base + LK - 1) & (LK - 1)][h] = s_partf[512 + h] + s_partf[768 + h];
        } else if (tid == 512) {
            int upd = 0, pos = 0;
            if (t >= LK) {
                float cs = s_scores[t - LK];
                int fill = s_fill;
                bool full = fill >= RS;
                upd = (!full) || (cs > s_minv);
                pos = full ? s_minp : fill;
                if (upd) { s_mask[pos] = 0.f; s_buck[pos] = cs; if (!full) s_fill = fill + 1; }
            }
            s_upd = upd; s_pos = pos;
        }
        __syncthreads();
        // F: gate matvec partials over st (4-way k-split); role 3 evicts oldest into bucket
        {
            constexpr int PER = USE_GX ? 32 : 48;   // 128 or 192 k2 total
            float af = 0.f, ai = 0.f, ao = 0.f, ag = 0.f;
            int lo = role * PER;
#pragma unroll 8
            for (int k2 = lo; k2 < lo + PER; ++k2) {
                float2 ss = *(const float2*)(s_in + 2 * k2);
                uint4 w = WP[k2 * NH + h];
                float2 f0 = __half22float2(*(const __half2*)&w.x);
                float2 f1 = __half22float2(*(const __half2*)&w.y);
                float2 f2 = __half22float2(*(const __half2*)&w.z);
                float2 f3 = __half22float2(*(const __half2*)&w.w);
                af += f0.x * ss.x + f0.y * ss.y; ai += f1.x * ss.x + f1.y * ss.y;
                ao += f2.x * ss.x + f2.y * ss.y; ag += f3.x * ss.x + f3.y * ss.y;
            }
            s_part4[role * NH + h] = make_float4(af, ai, ao, ag);
            if (role == 3 && s_upd) {
                int p0 = base & (LK - 1), pos = s_pos;
                lraw[pos * NH + h] = s_mem[p0][h];
                lua[pos * NH + h]  = s_memua[p0][h];
            }
        }
        __syncthreads();
        // G: combine + gate_x + activations + output + ring push
        if (tid < NH) {
            float4 A = s_part4[h], B4 = s_part4[NH + h], C4 = s_part4[2 * NH + h], D4 = s_part4[3 * NH + h];
            float pf = A.x + B4.x + C4.x + D4.x;
            float pi = A.y + B4.y + C4.y + D4.y;
            float po = A.z + B4.z + C4.z + D4.z;
            float pg = A.w + B4.w + C4.w + D4.w;
            if (USE_GX) {
                float2 fi = __half22float2(*(const __half2*)&gx.x);
                float2 og = __half22float2(*(const __half2*)&gx.y);
                pf += fi.x; pi += fi.y; po += og.x; pg += og.y;
            }
            float f  = fsig(pf + bfv);
            float ii = fsig(pi + biv);
            float o  = fsig(po + bov);
            float g  = ftanh(pg + bgv);
            ct = f * ct + ii * g;
            float hid = o * ftanh(ct);
            s_hid[h] = hid;
            out[((size_t)t * NB + b) * NH + h] = hid;
            s_mem[base & (LK - 1)][h] = hid;
        }
        base++;
        __syncthreads();
    }
}

extern "C" void kernel_launch(void* const* d_in, const int* in_sizes, int n_in,
                              void* d_out, int out_size, void* d_ws, size_t ws_size,
                              hipStream_t stream) {
    const float* x  = (const float*)d_in[0];
    const float* Wf = (const float*)d_in[1];
    const float* bf = (const float*)d_in[2];
    const float* Wi = (const float*)d_in[3];
    const float* bi = (const float*)d_in[4];
    const float* Wo = (const float*)d_in[5];
    const float* bo = (const float*)d_in[6];
    const float* Wg = (const float*)d_in[7];
    const float* bg = (const float*)d_in[8];
    const float* Ua = (const float*)d_in[9];
    const float* Va = (const float*)d_in[10];
    const float* vv = (const float*)d_in[11];
    unsigned char* ws = (unsigned char*)d_ws;
    float* out = (float*)d_out;

    prep_weights<<<256, 256, 0, stream>>>(Wf, Wi, Wo, Wg, Ua, Va, ws);
    if (ws_size >= WS_NEED) {
        gx_gemm<<<dim3(T_STEPS, 4), 256, 0, stream>>>(x, ws);
        rel_lstm<1><<<NB, 1024, 0, stream>>>(x, bf, bi, bo, bg, vv, ws, out);
    } else {
        rel_lstm<0><<<NB, 1024, 0, stream>>>(x, bf, bi, bo, bg, vv, ws, out);
    }
}